// Round 11
// baseline (218.248 us; speedup 1.0000x reference)
//
#include <hip/hip_runtime.h>
#include <climits>

typedef __attribute__((ext_vector_type(8))) short s8;      // 8 bf16 = 4 VGPRs
typedef __attribute__((ext_vector_type(4))) float f32x4;   // MFMA acc

#define BQ    256
#define DDIM  256
#define NBANK 100000
#define BN    64                          // bank cols per tile
#define NJB   ((NBANK + BN - 1) / BN)     // 1563
#define SENT  1e30f

// Split fp32 x into bf16 hi (round-half-up) + bf16 lo: x ~= hi + lo
__device__ inline void splitElem(float x, s8& h, s8& l, int i) {
    unsigned u  = __float_as_uint(x);
    unsigned uh = (u + 0x8000u) & 0xFFFF0000u;
    h[i] = (short)(uh >> 16);
    float lf = x - __uint_as_float(uh);            // exact
    l[i] = (short)((__float_as_uint(lf) + 0x8000u) >> 16);
}

__device__ inline void split8(const float4 v0, const float4 v1, s8& h, s8& l) {
    splitElem(v0.x, h, l, 0); splitElem(v0.y, h, l, 1);
    splitElem(v0.z, h, l, 2); splitElem(v0.w, h, l, 3);
    splitElem(v1.x, h, l, 4); splitElem(v1.y, h, l, 5);
    splitElem(v1.z, h, l, 6); splitElem(v1.w, h, l, 7);
}

__device__ inline float sq8(const float4 v0, const float4 v1, float s) {
    s = fmaf(v0.x, v0.x, s); s = fmaf(v0.y, v0.y, s);
    s = fmaf(v0.z, v0.z, s); s = fmaf(v0.w, v0.w, s);
    s = fmaf(v1.x, v1.x, s); s = fmaf(v1.y, v1.y, s);
    s = fmaf(v1.z, v1.z, s); s = fmaf(v1.w, v1.w, s);
    return s;
}

// Order-preserving float->u32 (monotone for ALL floats incl. negatives)
__device__ inline unsigned fkey(float f) {
    unsigned u = __float_as_uint(f);
    return u ^ (((int)u < 0) ? 0xFFFFFFFFu : 0x80000000u);
}

// Kernel 0: pre-split the tiny A (feature) into MFMA-A-fragment-ordered bf16 hi/lo.
__global__ __launch_bounds__(512) void split_feature(
    const float* __restrict__ feature, s8* __restrict__ fH, s8* __restrict__ fL)
{
    const int t    = blockIdx.x * 512 + threadIdx.x;   // 0..8191
    const int lane = t & 63, ks = (t >> 6) & 7, rt = t >> 9;
    const int row  = rt * 16 + (lane & 15);
    const int k0   = ks * 32 + (lane >> 4) * 8;
    const float* p = feature + (size_t)row * DDIM + k0;
    const float4 v0 = *(const float4*)p;
    const float4 v1 = *(const float4*)(p + 4);
    s8 h, l;
    split8(v0, v1, h, l);
    fH[t] = h; fL[t] = l;
}

// Kernel 1: 1024-thread FULL-M half-K GEMM + fused masked argmin.
// Ledger-driven restructure of R9 (90.1 us best):
//  - Occupancy: every 512-thr variant reads 36-40% occ; the 1024-thr R5 read
//    73% (residency packs 16 waves/block). Adopt 1024 thr WITHOUT R5's fatal
//    64-reg forced cap: launch_bounds(1024,4) = 128-reg cap, R9-proven ratio.
//  - No M-split: one block covers all 256 rows (16 waves x 1 row-tile,
//    acc[4] = 16 accs = R9's register-light shape) -> B staged ONCE, not
//    twice: per-thread staging halves (1 octet/half), split-VALU halves.
//  - R5's exact XOR swizzle (measured 0 conflicts), R9's u64 tie-exact keys,
//    3-MFMA scheme (absmax-0-validated R8/R9).
__global__ __launch_bounds__(1024, 4) void gemm_argmin_fullm(
    const s8* __restrict__ fH, const s8* __restrict__ fL,
    const float* __restrict__ bank,
    const int* __restrict__ cluster_label, const int* __restrict__ class_label,
    const int* __restrict__ cluster_idx,  const int* __restrict__ gt_label,
    unsigned long long* __restrict__ wsP, unsigned long long* __restrict__ wsD)
{
    __shared__ __align__(16) s8 bHs[4 * 4 * 64];   // [sl][ct][fraglane] 16 KB
    __shared__ __align__(16) s8 bLs[4 * 4 * 64];   // 16 KB
    __shared__ float b2s[BN];
    __shared__ int clsS[BN], cluS[BN], rowGt[BQ], rowClu[BQ];

    const int tid = threadIdx.x;
    const int jb  = blockIdx.x;
    const int j0  = jb * BN;

    // Staging role: col = tid>>4 (0..63), q = tid&15; per half: one 8-float octet
    const int col = tid >> 4, q = tid & 15;
    const int ct_s = col >> 4, cl_s = col & 15;
    const int sl_s = q >> 2, o_s = q & 3;          // slice-in-half, octet-in-slice
    // Compute/epilogue role: wave w (0..15) owns row-tile w
    const int w = tid >> 6, lane = tid & 63;
    const int g = lane >> 4, c = lane & 15;

    int jcol = j0 + col; if (jcol >= NBANK) jcol = NBANK - 1;
    const float* gb = bank + (size_t)jcol * DDIM + q * 8;    // +128 for half 1

    // ---- Prologue: labels + half-0 loads (8 floats/thread)
    if (tid < BQ) {
        rowGt[tid]  = gt_label[tid];
        rowClu[tid] = cluster_idx[tid];
    }
    if (tid < BN) {
        int jg = j0 + tid; int jc = jg < NBANK ? jg : NBANK - 1;
        clsS[tid] = class_label[jc];
        cluS[tid] = cluster_label[jc];
    }
    float4 a0 = *(const float4*)(gb);
    float4 a1 = *(const float4*)(gb + 4);

    // ---- Stage half 0 (slices 0..3). Writer XOR ^q (R5-verified: 0 conflicts).
    float sqa = 0.f;
    {
        s8 h, l;
        split8(a0, a1, h, l);
        sqa = sq8(a0, a1, sqa);
        const int wi = (((sl_s * 4 + ct_s) * 64 + o_s * 16 + cl_s)) ^ q;
        bHs[wi] = h; bLs[wi] = l;
    }
    __syncthreads();                       // bar1: half-0 staged

    // ---- Issue half-1 loads NOW; land under compute-h0 (only 8 VGPRs held)
    a0 = *(const float4*)(gb + 128);
    a1 = *(const float4*)(gb + 132);

    f32x4 acc[4];
    #pragma unroll
    for (int ct = 0; ct < 4; ++ct)
        acc[ct] = (f32x4){0.f, 0.f, 0.f, 0.f};

    // ---- Compute half 0: global slices 0..3; 48 MFMAs/wave per half
    #pragma unroll
    for (int sl = 0; sl < 4; ++sl) {
        const s8 aH = fH[(w * 8 + sl) * 64 + lane];
        const s8 aL = fL[(w * 8 + sl) * 64 + lane];
        const int rx = sl * 4 + g;                  // = writer's q for this slot
        #pragma unroll
        for (int ct = 0; ct < 4; ++ct) {
            const s8 bh = bHs[((sl * 4 + ct) * 64 + lane) ^ rx];
            const s8 bl = bLs[((sl * 4 + ct) * 64 + lane) ^ rx];
            acc[ct] = __builtin_amdgcn_mfma_f32_16x16x32_bf16(aH, bh, acc[ct], 0, 0, 0);
            acc[ct] = __builtin_amdgcn_mfma_f32_16x16x32_bf16(aH, bl, acc[ct], 0, 0, 0);
            acc[ct] = __builtin_amdgcn_mfma_f32_16x16x32_bf16(aL, bh, acc[ct], 0, 0, 0);
        }
    }
    __syncthreads();                       // bar2: all reads of half-0 LDS done

    // ---- Stage half 1 (slices 4..7 overwrite the same buffers)
    {
        s8 h, l;
        split8(a0, a1, h, l);
        sqa = sq8(a0, a1, sqa);
        const int wi = (((sl_s * 4 + ct_s) * 64 + o_s * 16 + cl_s)) ^ q;
        bHs[wi] = h; bLs[wi] = l;
    }
    // ||b||^2 over full K: the 16 q-threads of each col are adjacent lanes
    sqa += __shfl_xor(sqa, 1);
    sqa += __shfl_xor(sqa, 2);
    sqa += __shfl_xor(sqa, 4);
    sqa += __shfl_xor(sqa, 8);
    if (q == 0) b2s[col] = sqa;
    __syncthreads();                       // bar3: half-1 staged, b2s visible

    // ---- Compute half 1: global slices 4..7
    #pragma unroll
    for (int sl = 0; sl < 4; ++sl) {
        const s8 aH = fH[(w * 8 + 4 + sl) * 64 + lane];
        const s8 aL = fL[(w * 8 + 4 + sl) * 64 + lane];
        const int rx = sl * 4 + g;
        #pragma unroll
        for (int ct = 0; ct < 4; ++ct) {
            const s8 bh = bHs[((sl * 4 + ct) * 64 + lane) ^ rx];
            const s8 bl = bLs[((sl * 4 + ct) * 64 + lane) ^ rx];
            acc[ct] = __builtin_amdgcn_mfma_f32_16x16x32_bf16(aH, bh, acc[ct], 0, 0, 0);
            acc[ct] = __builtin_amdgcn_mfma_f32_16x16x32_bf16(aH, bl, acc[ct], 0, 0, 0);
            acc[ct] = __builtin_amdgcn_mfma_f32_16x16x32_bf16(aL, bh, acc[ct], 0, 0, 0);
        }
    }

    // ---- Epilogue: C/D layout col = lane&15, row = g*4 + reg (HW-verified).
    // u64 keys: min over candidates, tie -> lower index automatically.
    #pragma unroll
    for (int r = 0; r < 4; ++r) {
        const int row  = w * 16 + g * 4 + r;       // global row 0..255
        const int myGt = rowGt[row], myClu = rowClu[row];
        unsigned long long pk = ~0ull, dk = ~0ull;
        #pragma unroll
        for (int ct = 0; ct < 4; ++ct) {
            const int li = ct * 16 + c;
            const int jg = j0 + li;
            const float sc = b2s[li] - 2.f * acc[ct][r];
            if (jg < NBANK && clsS[li] != myGt) {
                const unsigned long long k =
                    ((unsigned long long)fkey(sc) << 32) | (unsigned)jg;
                dk = k < dk ? k : dk;
                if (cluS[li] == myClu) pk = k < pk ? k : pk;
            }
        }
        #pragma unroll
        for (int off = 1; off < 16; off <<= 1) {   // 16-lane u64 min-reduce
            unsigned long long ok = __shfl_xor(pk, off);
            pk = ok < pk ? ok : pk;
            ok = __shfl_xor(dk, off);
            dk = ok < dk ? ok : dk;
        }
        if (c == 0) {
            const size_t o = (size_t)jb * BQ + row;   // [jb][row]: 2 KB runs
            wsP[o] = pk;
            wsD[o] = dk;
        }
    }
}

// Kernel 2: per-row u64-min over NJB partials, fallback select, gather bank row.
__global__ __launch_bounds__(256) void reduce_gather(
    const unsigned long long* __restrict__ wsP,
    const unsigned long long* __restrict__ wsD,
    const float* __restrict__ bank, float* __restrict__ out)
{
    const int row = blockIdx.x, tid = threadIdx.x;
    unsigned long long pk = ~0ull, dk = ~0ull;
    for (int b = tid; b < NJB; b += 256) {
        unsigned long long k = wsP[(size_t)b * BQ + row];
        pk = k < pk ? k : pk;
        k = wsD[(size_t)b * BQ + row];
        dk = k < dk ? k : dk;
    }
    #pragma unroll
    for (int off = 32; off > 0; off >>= 1) {
        unsigned long long ok = __shfl_down(pk, off);
        pk = ok < pk ? ok : pk;
        ok = __shfl_down(dk, off);
        dk = ok < dk ? ok : dk;
    }
    __shared__ unsigned long long swP[4], swD[4];
    __shared__ int sIdx;
    const int lane = tid & 63, wv = tid >> 6;
    if (lane == 0) { swP[wv] = pk; swD[wv] = dk; }
    __syncthreads();
    if (tid == 0) {
        unsigned long long p = swP[0], d = swD[0];
        #pragma unroll
        for (int k2 = 1; k2 < 4; ++k2) {
            p = swP[k2] < p ? swP[k2] : p;
            d = swD[k2] < d ? swD[k2] : d;
        }
        sIdx = (p != ~0ull) ? (int)(unsigned)(p & 0xFFFFFFFFull)
             : ((d != ~0ull) ? (int)(unsigned)(d & 0xFFFFFFFFull) : 0);
    }
    __syncthreads();
    out[(size_t)row * DDIM + tid] = bank[(size_t)sIdx * DDIM + tid];
}

extern "C" void kernel_launch(void* const* d_in, const int* in_sizes, int n_in,
                              void* d_out, int out_size, void* d_ws, size_t ws_size,
                              hipStream_t stream) {
    const float* feature       = (const float*)d_in[0];
    const float* bank          = (const float*)d_in[1];
    const int*   cluster_label = (const int*)d_in[2];
    const int*   class_label   = (const int*)d_in[3];
    const int*   cluster_idx   = (const int*)d_in[4];
    const int*   gt_label      = (const int*)d_in[5];
    float* out = (float*)d_out;

    // Workspace: fH/fL (128 KB each) + 2 u64 key arrays [NJB][256] (3.2 MB each)
    s8* fH = (s8*)d_ws;                 // 8192 frags
    s8* fL = fH + 8192;
    unsigned long long* wsP = (unsigned long long*)((char*)d_ws + 2 * 8192 * sizeof(s8));
    unsigned long long* wsD = wsP + (size_t)BQ * NJB;

    hipLaunchKernelGGL(split_feature, dim3(16), dim3(512), 0, stream, feature, fH, fL);
    hipLaunchKernelGGL(gemm_argmin_fullm, dim3(NJB), dim3(1024), 0, stream,
                       fH, fL, bank, cluster_label, class_label, cluster_idx, gt_label,
                       wsP, wsD);
    hipLaunchKernelGGL(reduce_gather, dim3(BQ), dim3(256), 0, stream,
                       wsP, wsD, bank, out);
}

// Round 12
// 212.150 us; speedup vs baseline: 1.0287x; 1.0287x over previous
//
#include <hip/hip_runtime.h>
#include <climits>

typedef __attribute__((ext_vector_type(8))) short s8;      // 8 bf16 = 4 VGPRs
typedef __attribute__((ext_vector_type(4))) float f32x4;   // MFMA acc

#define BQ    256
#define DDIM  256
#define NBANK 100000
#define BN    64                          // bank cols per tile
#define NJB   ((NBANK + BN - 1) / BN)     // 1563
#define SENT  1e30f

// Split fp32 x into bf16 hi (round-half-up) + bf16 lo: x ~= hi + lo
__device__ inline void splitElem(float x, s8& h, s8& l, int i) {
    unsigned u  = __float_as_uint(x);
    unsigned uh = (u + 0x8000u) & 0xFFFF0000u;
    h[i] = (short)(uh >> 16);
    float lf = x - __uint_as_float(uh);            // exact
    l[i] = (short)((__float_as_uint(lf) + 0x8000u) >> 16);
}

__device__ inline void split8(const float4 v0, const float4 v1, s8& h, s8& l) {
    splitElem(v0.x, h, l, 0); splitElem(v0.y, h, l, 1);
    splitElem(v0.z, h, l, 2); splitElem(v0.w, h, l, 3);
    splitElem(v1.x, h, l, 4); splitElem(v1.y, h, l, 5);
    splitElem(v1.z, h, l, 6); splitElem(v1.w, h, l, 7);
}

__device__ inline float sq8(const float4 v0, const float4 v1, float s) {
    s = fmaf(v0.x, v0.x, s); s = fmaf(v0.y, v0.y, s);
    s = fmaf(v0.z, v0.z, s); s = fmaf(v0.w, v0.w, s);
    s = fmaf(v1.x, v1.x, s); s = fmaf(v1.y, v1.y, s);
    s = fmaf(v1.z, v1.z, s); s = fmaf(v1.w, v1.w, s);
    return s;
}

// Order-preserving float->u32 (monotone for ALL floats incl. negatives)
__device__ inline unsigned fkey(float f) {
    unsigned u = __float_as_uint(f);
    return u ^ (((int)u < 0) ? 0xFFFFFFFFu : 0x80000000u);
}

// Kernel 0: pre-split the tiny A (feature) into MFMA-A-fragment-ordered bf16 hi/lo.
__global__ __launch_bounds__(512) void split_feature(
    const float* __restrict__ feature, s8* __restrict__ fH, s8* __restrict__ fL)
{
    const int t    = blockIdx.x * 512 + threadIdx.x;   // 0..8191
    const int lane = t & 63, ks = (t >> 6) & 7, rt = t >> 9;
    const int row  = rt * 16 + (lane & 15);
    const int k0   = ks * 32 + (lane >> 4) * 8;
    const float* p = feature + (size_t)row * DDIM + k0;
    const float4 v0 = *(const float4*)p;
    const float4 v1 = *(const float4*)(p + 4);
    s8 h, l;
    split8(v0, v1, h, l);
    fH[t] = h; fL[t] = l;
}

// Kernel 1: rt=2 FULL-M half-K GEMM + fused masked argmin.
// LDS-PORT theory (R9/R10/R11 all plateau at ~91 us; accounting says the CU's
// single LDS port carries ~62 us: B-frag ds_read_b128 12.3k cy/tile + epilogue
// u64 shuffles 12.3k cy/tile): each wave now owns TWO row-tiles (acc[4][2]),
// so each B fragment is read once per (sl,ct) and reused for both row-tiles ->
// B-frag LDS reads halve. 512 thr / 8 waves; staging = R9's exact 2-octet
// mapping + ^q swizzle (measured 0 conflicts); C/D row = w*32+rt*16+g*4+r
// (R2-verified, absmax 0); 3-MFMA scheme (absmax-0 R8/R9); u64 tie-exact keys.
__global__ __launch_bounds__(512, 4) void gemm_argmin_rt2(
    const s8* __restrict__ fH, const s8* __restrict__ fL,
    const float* __restrict__ bank,
    const int* __restrict__ cluster_label, const int* __restrict__ class_label,
    const int* __restrict__ cluster_idx,  const int* __restrict__ gt_label,
    unsigned long long* __restrict__ wsP, unsigned long long* __restrict__ wsD)
{
    __shared__ __align__(16) s8 bHs[4 * 4 * 64];   // [sl][ct][fraglane] 16 KB
    __shared__ __align__(16) s8 bLs[4 * 4 * 64];   // 16 KB
    __shared__ float b2s[BN];
    __shared__ int clsS[BN], cluS[BN], rowGt[BQ], rowClu[BQ];

    const int tid = threadIdx.x;
    const int jb  = blockIdx.x;
    const int j0  = jb * BN;

    // Staging role: col = tid>>3 (0..63), q = tid&7; per half: two 8-float octets
    const int col = tid >> 3, q = tid & 7;
    const int ct_s = col >> 4, cl_s = col & 15;
    const int sl_s = q >> 1, p_s = q & 1;          // slice-in-half, octet-pair
    // Compute/epilogue role: wave w (0..7) owns row-tiles w*2, w*2+1
    const int w = tid >> 6, lane = tid & 63;
    const int g = lane >> 4, c = lane & 15;

    int jcol = j0 + col; if (jcol >= NBANK) jcol = NBANK - 1;
    const float* gb = bank + (size_t)jcol * DDIM + q * 16;   // +128 for half 1

    // ---- Prologue: labels + half-0 loads (16 floats/thread)
    if (tid < BQ) {
        rowGt[tid]  = gt_label[tid];
        rowClu[tid] = cluster_idx[tid];
    }
    if (tid < BN) {
        int jg = j0 + tid; int jc = jg < NBANK ? jg : NBANK - 1;
        clsS[tid] = class_label[jc];
        cluS[tid] = cluster_label[jc];
    }
    float4 a0 = *(const float4*)(gb);
    float4 a1 = *(const float4*)(gb + 4);
    float4 a2 = *(const float4*)(gb + 8);
    float4 a3 = *(const float4*)(gb + 12);

    // ---- Stage half 0 (slices 0..3). Writer XOR ^q (R9-verified: 0 conflicts).
    float sqa = 0.f;
    {
        s8 h, l;
        split8(a0, a1, h, l);
        sqa = sq8(a0, a1, sqa);
        int wi = (((sl_s * 4 + ct_s) * 64 + (p_s * 2 + 0) * 16 + cl_s)) ^ q;
        bHs[wi] = h; bLs[wi] = l;
        split8(a2, a3, h, l);
        sqa = sq8(a2, a3, sqa);
        wi = (((sl_s * 4 + ct_s) * 64 + (p_s * 2 + 1) * 16 + cl_s)) ^ q;
        bHs[wi] = h; bLs[wi] = l;
    }
    __syncthreads();                       // bar1: half-0 staged

    // ---- Issue half-1 loads NOW; land under compute-h0 (16 VGPRs held)
    a0 = *(const float4*)(gb + 128);
    a1 = *(const float4*)(gb + 132);
    a2 = *(const float4*)(gb + 136);
    a3 = *(const float4*)(gb + 140);

    f32x4 acc[4][2];
    #pragma unroll
    for (int ct = 0; ct < 4; ++ct)
        #pragma unroll
        for (int rt = 0; rt < 2; ++rt)
            acc[ct][rt] = (f32x4){0.f, 0.f, 0.f, 0.f};

    // ---- Compute half 0: slices 0..3. B-frags read ONCE per (sl,ct), reused
    // for both row-tiles: per-wave LDS b-reads halve vs rt=1.
    #pragma unroll
    for (int sl = 0; sl < 4; ++sl) {
        s8 aH[2], aL[2];
        #pragma unroll
        for (int rt = 0; rt < 2; ++rt) {
            const int RT = w * 2 + rt;
            aH[rt] = fH[(RT * 8 + sl) * 64 + lane];
            aL[rt] = fL[(RT * 8 + sl) * 64 + lane];
        }
        const int rx = sl * 2 + (lane >> 5);       // = writer's q for this slot
        #pragma unroll
        for (int ct = 0; ct < 4; ++ct) {
            const s8 bh = bHs[((sl * 4 + ct) * 64 + lane) ^ rx];
            const s8 bl = bLs[((sl * 4 + ct) * 64 + lane) ^ rx];
            #pragma unroll
            for (int rt = 0; rt < 2; ++rt) {
                acc[ct][rt] = __builtin_amdgcn_mfma_f32_16x16x32_bf16(aH[rt], bh, acc[ct][rt], 0, 0, 0);
                acc[ct][rt] = __builtin_amdgcn_mfma_f32_16x16x32_bf16(aH[rt], bl, acc[ct][rt], 0, 0, 0);
                acc[ct][rt] = __builtin_amdgcn_mfma_f32_16x16x32_bf16(aL[rt], bh, acc[ct][rt], 0, 0, 0);
            }
        }
    }
    __syncthreads();                       // bar2: all reads of half-0 LDS done

    // ---- Stage half 1 (slices 4..7 overwrite the same buffers)
    {
        s8 h, l;
        split8(a0, a1, h, l);
        sqa = sq8(a0, a1, sqa);
        int wi = (((sl_s * 4 + ct_s) * 64 + (p_s * 2 + 0) * 16 + cl_s)) ^ q;
        bHs[wi] = h; bLs[wi] = l;
        split8(a2, a3, h, l);
        sqa = sq8(a2, a3, sqa);
        wi = (((sl_s * 4 + ct_s) * 64 + (p_s * 2 + 1) * 16 + cl_s)) ^ q;
        bHs[wi] = h; bLs[wi] = l;
    }
    // ||b||^2 over full K: 8 q-threads of each col are adjacent lanes
    sqa += __shfl_xor(sqa, 1);
    sqa += __shfl_xor(sqa, 2);
    sqa += __shfl_xor(sqa, 4);
    if (q == 0) b2s[col] = sqa;
    __syncthreads();                       // bar3: half-1 staged, b2s visible

    // ---- Compute half 1: slices 4..7
    #pragma unroll
    for (int sl = 0; sl < 4; ++sl) {
        s8 aH[2], aL[2];
        #pragma unroll
        for (int rt = 0; rt < 2; ++rt) {
            const int RT = w * 2 + rt;
            aH[rt] = fH[(RT * 8 + 4 + sl) * 64 + lane];
            aL[rt] = fL[(RT * 8 + 4 + sl) * 64 + lane];
        }
        const int rx = sl * 2 + (lane >> 5);
        #pragma unroll
        for (int ct = 0; ct < 4; ++ct) {
            const s8 bh = bHs[((sl * 4 + ct) * 64 + lane) ^ rx];
            const s8 bl = bLs[((sl * 4 + ct) * 64 + lane) ^ rx];
            #pragma unroll
            for (int rt = 0; rt < 2; ++rt) {
                acc[ct][rt] = __builtin_amdgcn_mfma_f32_16x16x32_bf16(aH[rt], bh, acc[ct][rt], 0, 0, 0);
                acc[ct][rt] = __builtin_amdgcn_mfma_f32_16x16x32_bf16(aH[rt], bl, acc[ct][rt], 0, 0, 0);
                acc[ct][rt] = __builtin_amdgcn_mfma_f32_16x16x32_bf16(aL[rt], bh, acc[ct][rt], 0, 0, 0);
            }
        }
    }

    // ---- Epilogue: C/D layout col = lane&15, row = w*32+rt*16+g*4+r
    // (R2-verified for this 8-wave/rt=2 shape, absmax 0). u64 tie-exact keys.
    #pragma unroll
    for (int rt = 0; rt < 2; ++rt) {
        #pragma unroll
        for (int r = 0; r < 4; ++r) {
            const int row  = w * 32 + rt * 16 + g * 4 + r;
            const int myGt = rowGt[row], myClu = rowClu[row];
            unsigned long long pk = ~0ull, dk = ~0ull;
            #pragma unroll
            for (int ct = 0; ct < 4; ++ct) {
                const int li = ct * 16 + c;
                const int jg = j0 + li;
                const float sc = b2s[li] - 2.f * acc[ct][rt][r];
                if (jg < NBANK && clsS[li] != myGt) {
                    const unsigned long long k =
                        ((unsigned long long)fkey(sc) << 32) | (unsigned)jg;
                    dk = k < dk ? k : dk;
                    if (cluS[li] == myClu) pk = k < pk ? k : pk;
                }
            }
            #pragma unroll
            for (int off = 1; off < 16; off <<= 1) {   // 16-lane u64 min-reduce
                unsigned long long ok = __shfl_xor(pk, off);
                pk = ok < pk ? ok : pk;
                ok = __shfl_xor(dk, off);
                dk = ok < dk ? ok : dk;
            }
            if (c == 0) {
                const size_t o = (size_t)jb * BQ + row;   // [jb][row]: 2 KB runs
                wsP[o] = pk;
                wsD[o] = dk;
            }
        }
    }
}

// Kernel 2: per-row u64-min over NJB partials, fallback select, gather bank row.
__global__ __launch_bounds__(256) void reduce_gather(
    const unsigned long long* __restrict__ wsP,
    const unsigned long long* __restrict__ wsD,
    const float* __restrict__ bank, float* __restrict__ out)
{
    const int row = blockIdx.x, tid = threadIdx.x;
    unsigned long long pk = ~0ull, dk = ~0ull;
    for (int b = tid; b < NJB; b += 256) {
        unsigned long long k = wsP[(size_t)b * BQ + row];
        pk = k < pk ? k : pk;
        k = wsD[(size_t)b * BQ + row];
        dk = k < dk ? k : dk;
    }
    #pragma unroll
    for (int off = 32; off > 0; off >>= 1) {
        unsigned long long ok = __shfl_down(pk, off);
        pk = ok < pk ? ok : pk;
        ok = __shfl_down(dk, off);
        dk = ok < dk ? ok : dk;
    }
    __shared__ unsigned long long swP[4], swD[4];
    __shared__ int sIdx;
    const int lane = tid & 63, wv = tid >> 6;
    if (lane == 0) { swP[wv] = pk; swD[wv] = dk; }
    __syncthreads();
    if (tid == 0) {
        unsigned long long p = swP[0], d = swD[0];
        #pragma unroll
        for (int k2 = 1; k2 < 4; ++k2) {
            p = swP[k2] < p ? swP[k2] : p;
            d = swD[k2] < d ? swD[k2] : d;
        }
        sIdx = (p != ~0ull) ? (int)(unsigned)(p & 0xFFFFFFFFull)
             : ((d != ~0ull) ? (int)(unsigned)(d & 0xFFFFFFFFull) : 0);
    }
    __syncthreads();
    out[(size_t)row * DDIM + tid] = bank[(size_t)sIdx * DDIM + tid];
}

extern "C" void kernel_launch(void* const* d_in, const int* in_sizes, int n_in,
                              void* d_out, int out_size, void* d_ws, size_t ws_size,
                              hipStream_t stream) {
    const float* feature       = (const float*)d_in[0];
    const float* bank          = (const float*)d_in[1];
    const int*   cluster_label = (const int*)d_in[2];
    const int*   class_label   = (const int*)d_in[3];
    const int*   cluster_idx   = (const int*)d_in[4];
    const int*   gt_label      = (const int*)d_in[5];
    float* out = (float*)d_out;

    // Workspace: fH/fL (128 KB each) + 2 u64 key arrays [NJB][256] (3.2 MB each)
    s8* fH = (s8*)d_ws;                 // 8192 frags
    s8* fL = fH + 8192;
    unsigned long long* wsP = (unsigned long long*)((char*)d_ws + 2 * 8192 * sizeof(s8));
    unsigned long long* wsD = wsP + (size_t)BQ * NJB;

    hipLaunchKernelGGL(split_feature, dim3(16), dim3(512), 0, stream, feature, fH, fL);
    hipLaunchKernelGGL(gemm_argmin_rt2, dim3(NJB), dim3(512), 0, stream,
                       fH, fL, bank, cluster_label, class_label, cluster_idx, gt_label,
                       wsP, wsD);
    hipLaunchKernelGGL(reduce_gather, dim3(BQ), dim3(256), 0, stream,
                       wsP, wsD, bank, out);
}

// Round 13
// 208.562 us; speedup vs baseline: 1.0464x; 1.0172x over previous
//
#include <hip/hip_runtime.h>
#include <climits>

typedef __attribute__((ext_vector_type(8))) short s8;      // 8 bf16 = 4 VGPRs
typedef __attribute__((ext_vector_type(4))) float f32x4;   // MFMA acc

#define BQ    256
#define DDIM  256
#define NBANK 100000
#define BN    64                          // bank cols per tile
#define NJB   ((NBANK + BN - 1) / BN)     // 1563
#define SENT  1e30f

// Split fp32 x into bf16 hi (round-half-up) + bf16 lo: x ~= hi + lo
__device__ inline void splitElem(float x, s8& h, s8& l, int i) {
    unsigned u  = __float_as_uint(x);
    unsigned uh = (u + 0x8000u) & 0xFFFF0000u;
    h[i] = (short)(uh >> 16);
    float lf = x - __uint_as_float(uh);            // exact
    l[i] = (short)((__float_as_uint(lf) + 0x8000u) >> 16);
}

__device__ inline void split8(const float4 v0, const float4 v1, s8& h, s8& l) {
    splitElem(v0.x, h, l, 0); splitElem(v0.y, h, l, 1);
    splitElem(v0.z, h, l, 2); splitElem(v0.w, h, l, 3);
    splitElem(v1.x, h, l, 4); splitElem(v1.y, h, l, 5);
    splitElem(v1.z, h, l, 6); splitElem(v1.w, h, l, 7);
}

__device__ inline float sq8(const float4 v0, const float4 v1, float s) {
    s = fmaf(v0.x, v0.x, s); s = fmaf(v0.y, v0.y, s);
    s = fmaf(v0.z, v0.z, s); s = fmaf(v0.w, v0.w, s);
    s = fmaf(v1.x, v1.x, s); s = fmaf(v1.y, v1.y, s);
    s = fmaf(v1.z, v1.z, s); s = fmaf(v1.w, v1.w, s);
    return s;
}

// Order-preserving float->u32 (monotone for ALL floats incl. negatives)
__device__ inline unsigned fkey(float f) {
    unsigned u = __float_as_uint(f);
    return u ^ (((int)u < 0) ? 0xFFFFFFFFu : 0x80000000u);
}

// Kernel 0: pre-split the tiny A (feature) into MFMA-A-fragment-ordered bf16 hi/lo.
__global__ __launch_bounds__(512) void split_feature(
    const float* __restrict__ feature, s8* __restrict__ fH, s8* __restrict__ fL)
{
    const int t    = blockIdx.x * 512 + threadIdx.x;   // 0..8191
    const int lane = t & 63, ks = (t >> 6) & 7, rt = t >> 9;
    const int row  = rt * 16 + (lane & 15);
    const int k0   = ks * 32 + (lane >> 4) * 8;
    const float* p = feature + (size_t)row * DDIM + k0;
    const float4 v0 = *(const float4*)p;
    const float4 v1 = *(const float4*)(p + 4);
    s8 h, l;
    split8(v0, v1, h, l);
    fH[t] = h; fL[t] = l;
}

// Kernel 1: R9's M-split half-K GEMM (best profiled: 90.1 us) + ONE change:
// A-FRAGMENT REGISTER PRELOAD. Post-mortem chain: R12 falsified the LDS-port
// theory (halving B-frag ds_reads made things WORSE); MFMA/VALU/HBM all far
// from limits; R9~R11 invariance to block count says a throughput/latency
// term survives all shapes. The un-audited consumer: 16 global_load_dwordx4
// of fH/fL EMBEDDED in the MFMA loop (VGPR 48 proves the compiler never
// hoisted them) -> each sl-iteration eats ~200cy L2 latency into its MFMAs.
// Fix: each wave loads its 8x{hi,lo} A-frags (64 VGPR) ONCE at kernel start,
// before the B loads; latency overlaps prologue+staging+barrier. MFMA loops
// become pure LDS+register. Live set ~112 < 128 cap (512,4). Static indices
// only (fully unrolled). 3-MFMA scheme + u64 tie-exact keys kept.
__global__ __launch_bounds__(512, 4) void gemm_argmin_apre(
    const s8* __restrict__ fH, const s8* __restrict__ fL,
    const float* __restrict__ bank,
    const int* __restrict__ cluster_label, const int* __restrict__ class_label,
    const int* __restrict__ cluster_idx,  const int* __restrict__ gt_label,
    unsigned long long* __restrict__ wsP, unsigned long long* __restrict__ wsD)
{
    __shared__ __align__(16) s8 bHs[4 * 4 * 64];   // [sl][ct][fraglane] 16 KB
    __shared__ __align__(16) s8 bLs[4 * 4 * 64];   // 16 KB
    __shared__ float b2s[BN];
    __shared__ int clsS[BN], cluS[BN], rowGt[128], rowClu[128];

    const int tid = threadIdx.x;
    const int bb  = blockIdx.x;
    const int jb  = bb >> 1, mh = bb & 1;          // bank tile, M-half
    const int j0  = jb * BN;
    const int r0  = mh * 128;

    // Staging role: col = tid>>3 (0..63), q = tid&7; per half: two 8-float octets
    const int col = tid >> 3, q = tid & 7;
    const int ct_s = col >> 4, cl_s = col & 15;
    const int sl_s = q >> 1, p_s = q & 1;          // slice-in-half, octet-pair
    // Compute/epilogue role: wave w (0..7) owns global row-tile mh*8 + w
    const int w = tid >> 6, lane = tid & 63;
    const int g = lane >> 4, c = lane & 15;
    const int RT = mh * 8 + w;

    // ---- A-frag preload: issue FIRST so L2 latency hides under everything below
    s8 aHr[8], aLr[8];
    #pragma unroll
    for (int s = 0; s < 8; ++s) {
        aHr[s] = fH[(RT * 8 + s) * 64 + lane];
        aLr[s] = fL[(RT * 8 + s) * 64 + lane];
    }

    int jcol = j0 + col; if (jcol >= NBANK) jcol = NBANK - 1;
    const float* gb = bank + (size_t)jcol * DDIM + q * 16;   // +128 for half 1

    // ---- Prologue: labels + half-0 loads (16 floats/thread)
    if (tid < 128) {
        rowGt[tid]  = gt_label[r0 + tid];
        rowClu[tid] = cluster_idx[r0 + tid];
    }
    if (tid < BN) {
        int jg = j0 + tid; int jc = jg < NBANK ? jg : NBANK - 1;
        clsS[tid] = class_label[jc];
        cluS[tid] = cluster_label[jc];
    }
    float4 a0 = *(const float4*)(gb);
    float4 a1 = *(const float4*)(gb + 4);
    float4 a2 = *(const float4*)(gb + 8);
    float4 a3 = *(const float4*)(gb + 12);

    // ---- Stage half 0 (slices 0..3). Writer XOR ^q (R9-verified: 0 conflicts).
    float sqa = 0.f;
    {
        s8 h, l;
        split8(a0, a1, h, l);
        sqa = sq8(a0, a1, sqa);
        int wi = (((sl_s * 4 + ct_s) * 64 + (p_s * 2 + 0) * 16 + cl_s)) ^ q;
        bHs[wi] = h; bLs[wi] = l;
        split8(a2, a3, h, l);
        sqa = sq8(a2, a3, sqa);
        wi = (((sl_s * 4 + ct_s) * 64 + (p_s * 2 + 1) * 16 + cl_s)) ^ q;
        bHs[wi] = h; bLs[wi] = l;
    }
    __syncthreads();                       // bar1: half-0 staged

    // ---- Issue half-1 loads NOW; land under compute-h0 (16 VGPRs held)
    a0 = *(const float4*)(gb + 128);
    a1 = *(const float4*)(gb + 132);
    a2 = *(const float4*)(gb + 136);
    a3 = *(const float4*)(gb + 140);

    f32x4 acc[4];
    #pragma unroll
    for (int ct = 0; ct < 4; ++ct)
        acc[ct] = (f32x4){0.f, 0.f, 0.f, 0.f};

    // ---- Compute half 0: slices 0..3; pure LDS+register (A in regs)
    #pragma unroll
    for (int sl = 0; sl < 4; ++sl) {
        const int rx = sl * 2 + (lane >> 5);       // = writer's q for this slot
        #pragma unroll
        for (int ct = 0; ct < 4; ++ct) {
            const s8 bh = bHs[((sl * 4 + ct) * 64 + lane) ^ rx];
            const s8 bl = bLs[((sl * 4 + ct) * 64 + lane) ^ rx];
            acc[ct] = __builtin_amdgcn_mfma_f32_16x16x32_bf16(aHr[sl], bh, acc[ct], 0, 0, 0);
            acc[ct] = __builtin_amdgcn_mfma_f32_16x16x32_bf16(aHr[sl], bl, acc[ct], 0, 0, 0);
            acc[ct] = __builtin_amdgcn_mfma_f32_16x16x32_bf16(aLr[sl], bh, acc[ct], 0, 0, 0);
        }
    }
    __syncthreads();                       // bar2: all reads of half-0 LDS done

    // ---- Stage half 1 (slices 4..7 overwrite the same buffers)
    {
        s8 h, l;
        split8(a0, a1, h, l);
        sqa = sq8(a0, a1, sqa);
        int wi = (((sl_s * 4 + ct_s) * 64 + (p_s * 2 + 0) * 16 + cl_s)) ^ q;
        bHs[wi] = h; bLs[wi] = l;
        split8(a2, a3, h, l);
        sqa = sq8(a2, a3, sqa);
        wi = (((sl_s * 4 + ct_s) * 64 + (p_s * 2 + 1) * 16 + cl_s)) ^ q;
        bHs[wi] = h; bLs[wi] = l;
    }
    // ||b||^2 over full K: 8 q-threads of each col are adjacent lanes
    sqa += __shfl_xor(sqa, 1);
    sqa += __shfl_xor(sqa, 2);
    sqa += __shfl_xor(sqa, 4);
    if (q == 0) b2s[col] = sqa;
    __syncthreads();                       // bar3: half-1 staged, b2s visible

    // ---- Compute half 1: slices 4..7
    #pragma unroll
    for (int sl = 0; sl < 4; ++sl) {
        const int rx = sl * 2 + (lane >> 5);
        #pragma unroll
        for (int ct = 0; ct < 4; ++ct) {
            const s8 bh = bHs[((sl * 4 + ct) * 64 + lane) ^ rx];
            const s8 bl = bLs[((sl * 4 + ct) * 64 + lane) ^ rx];
            acc[ct] = __builtin_amdgcn_mfma_f32_16x16x32_bf16(aHr[4 + sl], bh, acc[ct], 0, 0, 0);
            acc[ct] = __builtin_amdgcn_mfma_f32_16x16x32_bf16(aHr[4 + sl], bl, acc[ct], 0, 0, 0);
            acc[ct] = __builtin_amdgcn_mfma_f32_16x16x32_bf16(aLr[4 + sl], bh, acc[ct], 0, 0, 0);
        }
    }

    // ---- Epilogue: C/D layout col = lane&15, row = g*4 + reg (HW-verified).
    // u64 keys: min over candidates, tie -> lower index automatically.
    #pragma unroll
    for (int r = 0; r < 4; ++r) {
        const int lrow = w * 16 + g * 4 + r;       // 0..127 within this M-half
        const int myGt = rowGt[lrow], myClu = rowClu[lrow];
        unsigned long long pk = ~0ull, dk = ~0ull;
        #pragma unroll
        for (int ct = 0; ct < 4; ++ct) {
            const int li = ct * 16 + c;
            const int jg = j0 + li;
            const float sc = b2s[li] - 2.f * acc[ct][r];
            if (jg < NBANK && clsS[li] != myGt) {
                const unsigned long long k =
                    ((unsigned long long)fkey(sc) << 32) | (unsigned)jg;
                dk = k < dk ? k : dk;
                if (cluS[li] == myClu) pk = k < pk ? k : pk;
            }
        }
        #pragma unroll
        for (int off = 1; off < 16; off <<= 1) {   // 16-lane u64 min-reduce
            unsigned long long ok = __shfl_xor(pk, off);
            pk = ok < pk ? ok : pk;
            ok = __shfl_xor(dk, off);
            dk = ok < dk ? ok : dk;
        }
        if (c == 0) {
            const size_t o = (size_t)jb * BQ + r0 + lrow;  // [jb][row]: 2 KB runs
            wsP[o] = pk;
            wsD[o] = dk;
        }
    }
}

// Kernel 2: per-row u64-min over NJB partials, fallback select, gather bank row.
__global__ __launch_bounds__(256) void reduce_gather(
    const unsigned long long* __restrict__ wsP,
    const unsigned long long* __restrict__ wsD,
    const float* __restrict__ bank, float* __restrict__ out)
{
    const int row = blockIdx.x, tid = threadIdx.x;
    unsigned long long pk = ~0ull, dk = ~0ull;
    for (int b = tid; b < NJB; b += 256) {
        unsigned long long k = wsP[(size_t)b * BQ + row];
        pk = k < pk ? k : pk;
        k = wsD[(size_t)b * BQ + row];
        dk = k < dk ? k : dk;
    }
    #pragma unroll
    for (int off = 32; off > 0; off >>= 1) {
        unsigned long long ok = __shfl_down(pk, off);
        pk = ok < pk ? ok : pk;
        ok = __shfl_down(dk, off);
        dk = ok < dk ? ok : dk;
    }
    __shared__ unsigned long long swP[4], swD[4];
    __shared__ int sIdx;
    const int lane = tid & 63, wv = tid >> 6;
    if (lane == 0) { swP[wv] = pk; swD[wv] = dk; }
    __syncthreads();
    if (tid == 0) {
        unsigned long long p = swP[0], d = swD[0];
        #pragma unroll
        for (int k2 = 1; k2 < 4; ++k2) {
            p = swP[k2] < p ? swP[k2] : p;
            d = swD[k2] < d ? swD[k2] : d;
        }
        sIdx = (p != ~0ull) ? (int)(unsigned)(p & 0xFFFFFFFFull)
             : ((d != ~0ull) ? (int)(unsigned)(d & 0xFFFFFFFFull) : 0);
    }
    __syncthreads();
    out[(size_t)row * DDIM + tid] = bank[(size_t)sIdx * DDIM + tid];
}

extern "C" void kernel_launch(void* const* d_in, const int* in_sizes, int n_in,
                              void* d_out, int out_size, void* d_ws, size_t ws_size,
                              hipStream_t stream) {
    const float* feature       = (const float*)d_in[0];
    const float* bank          = (const float*)d_in[1];
    const int*   cluster_label = (const int*)d_in[2];
    const int*   class_label   = (const int*)d_in[3];
    const int*   cluster_idx   = (const int*)d_in[4];
    const int*   gt_label      = (const int*)d_in[5];
    float* out = (float*)d_out;

    // Workspace: fH/fL (128 KB each) + 2 u64 key arrays [NJB][256] (3.2 MB each)
    s8* fH = (s8*)d_ws;                 // 8192 frags
    s8* fL = fH + 8192;
    unsigned long long* wsP = (unsigned long long*)((char*)d_ws + 2 * 8192 * sizeof(s8));
    unsigned long long* wsD = wsP + (size_t)BQ * NJB;

    hipLaunchKernelGGL(split_feature, dim3(16), dim3(512), 0, stream, feature, fH, fL);
    hipLaunchKernelGGL(gemm_argmin_apre, dim3(NJB * 2), dim3(512), 0, stream,
                       fH, fL, bank, cluster_label, class_label, cluster_idx, gt_label,
                       wsP, wsD);
    hipLaunchKernelGGL(reduce_gather, dim3(BQ), dim3(256), 0, stream,
                       wsP, wsD, bank, out);
}